// Round 2
// baseline (1202.661 us; speedup 1.0000x reference)
//
#include <hip/hip_runtime.h>

// ---------------------------------------------------------------------------
// 2-layer GCN (PyG GCNConv semantics): deg^{-1/2} sym norm w/ self-loops.
//   deg[i]  = 1 + in-degree(i)
//   dinv[i] = rsqrt(deg[i])
// Linearity: agg(x @ W) == agg(x) @ W, so layer 1 aggregates first (saves a
// full N x 128 buffer), layer 2 transforms first (aggregates at 64-wide).
//   L1: aggX = selfloop(x) + edges(x);  h = relu(aggX @ W1 + b1)   [in-place]
//   L2: t = h @ W2;  out = selfloop(t) + b2 + edges(t)
// edge_index arrives as int32 (harness converts integer inputs to int32).
// ---------------------------------------------------------------------------

#define NTHREADS 256

__global__ void deg_init_k(float* __restrict__ deg, int n) {
    int i = blockIdx.x * NTHREADS + threadIdx.x;
    if (i < n) deg[i] = 1.0f;  // self-loop
}

__global__ void deg_count_k(const int* __restrict__ dst,
                            float* __restrict__ deg, int e) {
    int i = blockIdx.x * NTHREADS + threadIdx.x;
    if (i < e) atomicAdd(&deg[dst[i]], 1.0f);
}

__global__ void dinv_k(float* __restrict__ deg, int n) {
    int i = blockIdx.x * NTHREADS + threadIdx.x;
    if (i < n) deg[i] = rsqrtf(deg[i]);
}

// ---------------------------------------------------------------------------
// C[nrows x OC] = A[nrows x 128] @ W[128 x OC] (+bias, relu optional).
// Safe for A == C: __syncthreads() separates all reads from all writes, and
// each block reads only rows it owns (clamped rows stay inside the last
// block's own range).
// ---------------------------------------------------------------------------
template <int OC, bool RELU, bool BIAS>
__global__ __launch_bounds__(NTHREADS) void gemm_k(
    const float* __restrict__ A, const float* __restrict__ W,
    const float* __restrict__ bias, float* __restrict__ C, int nrows) {
    constexpr int TC  = 16;                     // cols per thread
    constexpr int TR  = 4;                      // rows per thread
    constexpr int NCG = OC / TC;                // col groups (8 or 4)
    constexpr int RPB = (NTHREADS / NCG) * TR;  // rows per block (128 or 256)

    __shared__ float sW[128 * OC];
    for (int i = threadIdx.x; i < 128 * OC / 4; i += NTHREADS)
        reinterpret_cast<float4*>(sW)[i] = reinterpret_cast<const float4*>(W)[i];
    __syncthreads();

    const int cg   = threadIdx.x % NCG;
    const int rg   = threadIdx.x / NCG;
    const int row0 = blockIdx.x * RPB + rg * TR;

    float acc[TR][TC];
#pragma unroll
    for (int r = 0; r < TR; ++r)
#pragma unroll
        for (int c = 0; c < TC; ++c) acc[r][c] = 0.0f;

    for (int kc = 0; kc < 128; kc += 4) {
        float4 a[TR];
#pragma unroll
        for (int r = 0; r < TR; ++r) {
            int row = row0 + r;
            if (row >= nrows) row = nrows - 1;  // clamped (store is guarded)
            a[r] = *reinterpret_cast<const float4*>(&A[(long long)row * 128 + kc]);
        }
#pragma unroll
        for (int kk = 0; kk < 4; ++kk) {
            float w[TC];
#pragma unroll
            for (int j = 0; j < TC / 4; ++j) {
                float4 wv = *reinterpret_cast<const float4*>(
                    &sW[(kc + kk) * OC + cg * TC + j * 4]);
                w[j * 4 + 0] = wv.x; w[j * 4 + 1] = wv.y;
                w[j * 4 + 2] = wv.z; w[j * 4 + 3] = wv.w;
            }
#pragma unroll
            for (int r = 0; r < TR; ++r) {
                float av = (kk == 0) ? a[r].x : (kk == 1) ? a[r].y
                         : (kk == 2) ? a[r].z : a[r].w;
#pragma unroll
                for (int c = 0; c < TC; ++c) acc[r][c] += av * w[c];
            }
        }
    }

    __syncthreads();  // all reads of A complete before any write (A==C safe)

#pragma unroll
    for (int r = 0; r < TR; ++r) {
        int row = row0 + r;
        if (row < nrows) {
#pragma unroll
            for (int c = 0; c < TC; ++c) {
                float v = acc[r][c];
                if (BIAS) v += bias[cg * TC + c];
                if (RELU) v = fmaxf(v, 0.0f);
                acc[r][c] = v;
            }
#pragma unroll
            for (int j = 0; j < TC / 4; ++j) {
                float4 v = make_float4(acc[r][j * 4 + 0], acc[r][j * 4 + 1],
                                       acc[r][j * 4 + 2], acc[r][j * 4 + 3]);
                *reinterpret_cast<float4*>(
                    &C[(long long)row * OC + cg * TC + j * 4]) = v;
            }
        }
    }
}

// agg[i,:] = h[i,:] * dinv[i]^2 (+ bias)   — initializes agg
template <int D, bool BIAS>
__global__ void selfloop_k(const float* __restrict__ h,
                           const float* __restrict__ dinv,
                           const float* __restrict__ bias,
                           float* __restrict__ agg, int n4) {
    int idx = blockIdx.x * NTHREADS + threadIdx.x;
    if (idx >= n4) return;
    int i = (idx * 4) / D;
    int c = (idx * 4) & (D - 1);
    float di = dinv[i];
    float s = di * di;
    float4 v = reinterpret_cast<const float4*>(h)[idx];
    v.x *= s; v.y *= s; v.z *= s; v.w *= s;
    if (BIAS) {
        v.x += bias[c + 0]; v.y += bias[c + 1];
        v.z += bias[c + 2]; v.w += bias[c + 3];
    }
    reinterpret_cast<float4*>(agg)[idx] = v;
}

// agg[dst,:] += h[src,:] * dinv[src]*dinv[dst]   (one 32-lane group per edge)
template <int D>
__global__ __launch_bounds__(NTHREADS) void edge_agg_k(
    const int* __restrict__ src, const int* __restrict__ dst,
    const float* __restrict__ dinv, const float* __restrict__ h,
    float* __restrict__ agg, int e) {
    int g = blockIdx.x * (NTHREADS / 32) + (threadIdx.x >> 5);
    int lane = threadIdx.x & 31;
    if (g >= e) return;
    int s = src[g];
    int d = dst[g];
    float nrm = dinv[s] * dinv[d];
    const float* hs = h + (long long)s * D;
    float* ad = agg + (long long)d * D;
#pragma unroll
    for (int j = 0; j < D / 32; ++j) {
        int c = lane + j * 32;
        atomicAdd(&ad[c], hs[c] * nrm);
    }
}

extern "C" void kernel_launch(void* const* d_in, const int* in_sizes, int n_in,
                              void* d_out, int out_size, void* d_ws, size_t ws_size,
                              hipStream_t stream) {
    const float* x   = (const float*)d_in[0];
    const int*   ei  = (const int*)d_in[1];
    const float* W1  = (const float*)d_in[2];
    const float* b1  = (const float*)d_in[3];
    const float* W2  = (const float*)d_in[4];
    const float* b2  = (const float*)d_in[5];
    float*       out = (float*)d_out;

    const int N = in_sizes[0] / 128;
    const int E = in_sizes[1] / 2;
    const int* srcp = ei;      // edge_index[0]
    const int* dstp = ei + E;  // edge_index[1]

    // workspace: dinv[N] | bufA[N*128] | bufB[N*64]   (~77.2 MB total)
    char* ws = (char*)d_ws;
    float* dinv = (float*)ws;
    size_t off = (((size_t)N * 4) + 511) & ~(size_t)511;
    float* bufA = (float*)(ws + off);
    float* bufB = (float*)(ws + off + (size_t)N * 128 * sizeof(float));

    // ---- degrees / norm ----
    deg_init_k<<<(N + NTHREADS - 1) / NTHREADS, NTHREADS, 0, stream>>>(dinv, N);
    deg_count_k<<<(E + NTHREADS - 1) / NTHREADS, NTHREADS, 0, stream>>>(dstp, dinv, E);
    dinv_k<<<(N + NTHREADS - 1) / NTHREADS, NTHREADS, 0, stream>>>(dinv, N);

    // ---- layer 1: aggregate x -> bufA, then in-place GEMM+bias+relu ----
    int n4a = N * 128 / 4;
    selfloop_k<128, false><<<(n4a + NTHREADS - 1) / NTHREADS, NTHREADS, 0, stream>>>(
        x, dinv, nullptr, bufA, n4a);
    edge_agg_k<128><<<(E + 7) / 8, NTHREADS, 0, stream>>>(srcp, dstp, dinv, x, bufA, E);
    gemm_k<128, true, true><<<(N + 127) / 128, NTHREADS, 0, stream>>>(
        bufA, W1, b1, bufA, N);

    // ---- layer 2: transform -> bufB, aggregate -> out (+b2 folded in) ----
    gemm_k<64, false, false><<<(N + 255) / 256, NTHREADS, 0, stream>>>(
        bufA, W2, nullptr, bufB, N);
    int n4b = N * 64 / 4;
    selfloop_k<64, true><<<(n4b + NTHREADS - 1) / NTHREADS, NTHREADS, 0, stream>>>(
        bufB, dinv, b2, out, n4b);
    edge_agg_k<64><<<(E + 7) / 8, NTHREADS, 0, stream>>>(srcp, dstp, dinv, bufB, out, E);
}

// Round 3
// 584.102 us; speedup vs baseline: 2.0590x; 2.0590x over previous
//
#include <hip/hip_runtime.h>

// ---------------------------------------------------------------------------
// 2-layer GCN (PyG GCNConv): deg^{-1/2} sym norm with self-loops.
// Round 3: replace per-edge fp32 atomics with device-built CSR (edges sorted
// by dst) + gather-side aggregation (one wave per destination node, register
// accumulation, single coalesced store). Removes ~1.2 GB of atomic RMW.
//
//   L1: aggX = selfloop(x) + gather(x);  h = relu(aggX @ W1 + b1) [in-place]
//   L2: t = h @ W2;  out = selfloop(t) + b2 + gather(t)
// ---------------------------------------------------------------------------

#define NT 256

// ---------------- CSR build ----------------

__global__ void zero_counts_k(int* __restrict__ c, int n) {
    int i = blockIdx.x * NT + threadIdx.x;
    if (i < n) c[i] = 0;
}

__global__ void deg_count_k(const int* __restrict__ dst, int* __restrict__ c, int e) {
    int i = blockIdx.x * NT + threadIdx.x;
    if (i < e) atomicAdd(&c[dst[i]], 1);
}

__global__ void dinv_k(const int* __restrict__ c, float* __restrict__ dinv, int n) {
    int i = blockIdx.x * NT + threadIdx.x;
    if (i < n) dinv[i] = rsqrtf((float)(c[i] + 1));  // +1 self-loop
}

// exclusive scan of counts -> rowptr, 3-phase (block scan, block-sum scan, add)
__global__ void scan1_k(const int* __restrict__ counts, int* __restrict__ rowptr,
                        int* __restrict__ bsum, int n) {
    __shared__ int s[NT];
    int tid = threadIdx.x, i = blockIdx.x * NT + tid;
    int v = (i < n) ? counts[i] : 0;
    s[tid] = v;
    __syncthreads();
    for (int off = 1; off < NT; off <<= 1) {
        int t = (tid >= off) ? s[tid - off] : 0;
        __syncthreads();
        if (tid >= off) s[tid] += t;
        __syncthreads();
    }
    if (i < n) rowptr[i] = s[tid] - v;  // exclusive within block
    if (tid == NT - 1) bsum[blockIdx.x] = s[tid];
}

__global__ void scan2_k(int* __restrict__ bsum, int nb) {
    __shared__ int s[512];
    __shared__ int carry;
    int tid = threadIdx.x;
    if (tid == 0) carry = 0;
    __syncthreads();
    for (int base = 0; base < nb; base += 512) {
        int i = base + tid;
        int v = (i < nb) ? bsum[i] : 0;
        s[tid] = v;
        __syncthreads();
        for (int off = 1; off < 512; off <<= 1) {
            int t = (tid >= off) ? s[tid - off] : 0;
            __syncthreads();
            if (tid >= off) s[tid] += t;
            __syncthreads();
        }
        int tot = s[511];
        if (i < nb) bsum[i] = s[tid] - v + carry;
        __syncthreads();
        if (tid == 0) carry += tot;
        __syncthreads();
    }
}

__global__ void scan3_k(int* __restrict__ rowptr, const int* __restrict__ bsum,
                        int* __restrict__ cursor, int n, int e) {
    int i = blockIdx.x * NT + threadIdx.x;
    if (i < n) {
        int r = rowptr[i] + bsum[i / NT];
        rowptr[i] = r;
        cursor[i] = r;
    } else if (i == n) {
        rowptr[n] = e;
    }
}

__global__ void scatter_k(const int* __restrict__ src, const int* __restrict__ dst,
                          int* __restrict__ cursor, int* __restrict__ srcs, int e) {
    int i = blockIdx.x * NT + threadIdx.x;
    if (i < e) {
        int pos = atomicAdd(&cursor[dst[i]], 1);
        srcs[pos] = src[i];
    }
}

// ---------------- gather aggregation (one wave per node) ----------------

// D=128: lane covers cols [2*lane, 2*lane+1] (float2); includes self-loop.
__global__ __launch_bounds__(NT) void gather128_k(
    const int* __restrict__ rowptr, const int* __restrict__ srcs,
    const float* __restrict__ dinv, const float* __restrict__ h,
    float* __restrict__ out, int n) {
    int node = blockIdx.x * (NT / 64) + (threadIdx.x >> 6);
    if (node >= n) return;
    int lane = threadIdx.x & 63;
    float dn = dinv[node];
    float sl = dn * dn;
    float2 hv = *reinterpret_cast<const float2*>(&h[(size_t)node * 128 + lane * 2]);
    float accx = hv.x * sl, accy = hv.y * sl;
    int e = rowptr[node], e1 = rowptr[node + 1];
    for (; e + 1 < e1; e += 2) {
        int s0 = srcs[e], s1 = srcs[e + 1];
        float n0 = dinv[s0] * dn, n1 = dinv[s1] * dn;
        float2 a = *reinterpret_cast<const float2*>(&h[(size_t)s0 * 128 + lane * 2]);
        float2 b = *reinterpret_cast<const float2*>(&h[(size_t)s1 * 128 + lane * 2]);
        accx = fmaf(a.x, n0, accx); accy = fmaf(a.y, n0, accy);
        accx = fmaf(b.x, n1, accx); accy = fmaf(b.y, n1, accy);
    }
    if (e < e1) {
        int s0 = srcs[e];
        float n0 = dinv[s0] * dn;
        float2 a = *reinterpret_cast<const float2*>(&h[(size_t)s0 * 128 + lane * 2]);
        accx = fmaf(a.x, n0, accx); accy = fmaf(a.y, n0, accy);
    }
    *reinterpret_cast<float2*>(&out[(size_t)node * 128 + lane * 2]) =
        make_float2(accx, accy);
}

// D=64: lane covers col lane; includes self-loop and +bias (b2).
__global__ __launch_bounds__(NT) void gather64_k(
    const int* __restrict__ rowptr, const int* __restrict__ srcs,
    const float* __restrict__ dinv, const float* __restrict__ h,
    const float* __restrict__ bias, float* __restrict__ out, int n) {
    int node = blockIdx.x * (NT / 64) + (threadIdx.x >> 6);
    if (node >= n) return;
    int lane = threadIdx.x & 63;
    float dn = dinv[node];
    float acc = h[(size_t)node * 64 + lane] * dn * dn + bias[lane];
    int e = rowptr[node], e1 = rowptr[node + 1];
    for (; e + 1 < e1; e += 2) {
        int s0 = srcs[e], s1 = srcs[e + 1];
        float n0 = dinv[s0] * dn, n1 = dinv[s1] * dn;
        float a = h[(size_t)s0 * 64 + lane];
        float b = h[(size_t)s1 * 64 + lane];
        acc = fmaf(a, n0, acc);
        acc = fmaf(b, n1, acc);
    }
    if (e < e1) {
        int s0 = srcs[e];
        acc = fmaf(h[(size_t)s0 * 64 + lane], dinv[s0] * dn, acc);
    }
    out[(size_t)node * 64 + lane] = acc;
}

// ---------------- dense GEMM (fp32 vector ALU, W in LDS) ----------------
// Safe for A == C: __syncthreads() separates all reads from all writes and
// each block reads only rows it writes.
template <int OC, bool RELU, bool BIAS>
__global__ __launch_bounds__(NT) void gemm_k(
    const float* __restrict__ A, const float* __restrict__ W,
    const float* __restrict__ bias, float* __restrict__ C, int nrows) {
    constexpr int TC  = 16;
    constexpr int TR  = 4;
    constexpr int NCG = OC / TC;
    constexpr int RPB = (NT / NCG) * TR;

    __shared__ float sW[128 * OC];
    for (int i = threadIdx.x; i < 128 * OC / 4; i += NT)
        reinterpret_cast<float4*>(sW)[i] = reinterpret_cast<const float4*>(W)[i];
    __syncthreads();

    const int cg   = threadIdx.x % NCG;
    const int rg   = threadIdx.x / NCG;
    const int row0 = blockIdx.x * RPB + rg * TR;

    float acc[TR][TC];
#pragma unroll
    for (int r = 0; r < TR; ++r)
#pragma unroll
        for (int c = 0; c < TC; ++c) acc[r][c] = 0.0f;

    for (int kc = 0; kc < 128; kc += 4) {
        float4 a[TR];
#pragma unroll
        for (int r = 0; r < TR; ++r) {
            int row = row0 + r;
            if (row >= nrows) row = nrows - 1;
            a[r] = *reinterpret_cast<const float4*>(&A[(long long)row * 128 + kc]);
        }
#pragma unroll
        for (int kk = 0; kk < 4; ++kk) {
            float w[TC];
#pragma unroll
            for (int j = 0; j < TC / 4; ++j) {
                float4 wv = *reinterpret_cast<const float4*>(
                    &sW[(kc + kk) * OC + cg * TC + j * 4]);
                w[j * 4 + 0] = wv.x; w[j * 4 + 1] = wv.y;
                w[j * 4 + 2] = wv.z; w[j * 4 + 3] = wv.w;
            }
#pragma unroll
            for (int r = 0; r < TR; ++r) {
                float av = (kk == 0) ? a[r].x : (kk == 1) ? a[r].y
                         : (kk == 2) ? a[r].z : a[r].w;
#pragma unroll
                for (int c = 0; c < TC; ++c) acc[r][c] += av * w[c];
            }
        }
    }

    __syncthreads();  // A==C safety

#pragma unroll
    for (int r = 0; r < TR; ++r) {
        int row = row0 + r;
        if (row < nrows) {
#pragma unroll
            for (int c = 0; c < TC; ++c) {
                float v = acc[r][c];
                if (BIAS) v += bias[cg * TC + c];
                if (RELU) v = fmaxf(v, 0.0f);
                acc[r][c] = v;
            }
#pragma unroll
            for (int j = 0; j < TC / 4; ++j) {
                float4 v = make_float4(acc[r][j * 4 + 0], acc[r][j * 4 + 1],
                                       acc[r][j * 4 + 2], acc[r][j * 4 + 3]);
                *reinterpret_cast<float4*>(
                    &C[(long long)row * OC + cg * TC + j * 4]) = v;
            }
        }
    }
}

// ---------------------------------------------------------------------------

extern "C" void kernel_launch(void* const* d_in, const int* in_sizes, int n_in,
                              void* d_out, int out_size, void* d_ws, size_t ws_size,
                              hipStream_t stream) {
    const float* x   = (const float*)d_in[0];
    const int*   ei  = (const int*)d_in[1];
    const float* W1  = (const float*)d_in[2];
    const float* b1  = (const float*)d_in[3];
    const float* W2  = (const float*)d_in[4];
    const float* b2  = (const float*)d_in[5];
    float*       out = (float*)d_out;

    const int N = in_sizes[0] / 128;
    const int E = in_sizes[1] / 2;
    const int* srcp = ei;      // edge_index[0]
    const int* dstp = ei + E;  // edge_index[1]

    const int nb = (N + NT - 1) / NT;  // scan blocks

    // workspace layout (512B-aligned):
    //   dinv[N] | counts/cursor[N] | rowptr[N+1] | bsum[nb] | srcs[E]
    //   | bufA[N*128] | bufB[N*64]     (~84.5 MB)
    char* ws = (char*)d_ws;
    size_t off = 0;
    auto alloc = [&](size_t bytes) {
        char* p = ws + off;
        off = (off + bytes + 511) & ~(size_t)511;
        return p;
    };
    float* dinv   = (float*)alloc((size_t)N * 4);
    int*   cnt    = (int*)alloc((size_t)N * 4);      // counts, then cursor
    int*   rowptr = (int*)alloc((size_t)(N + 1) * 4);
    int*   bsum   = (int*)alloc((size_t)nb * 4);
    int*   srcs   = (int*)alloc((size_t)E * 4);
    float* bufA   = (float*)alloc((size_t)N * 128 * 4);
    float* bufB   = (float*)alloc((size_t)N * 64 * 4);

    // ---- CSR build + norm ----
    zero_counts_k<<<nb, NT, 0, stream>>>(cnt, N);
    deg_count_k<<<(E + NT - 1) / NT, NT, 0, stream>>>(dstp, cnt, E);
    dinv_k<<<nb, NT, 0, stream>>>(cnt, dinv, N);
    scan1_k<<<nb, NT, 0, stream>>>(cnt, rowptr, bsum, N);
    scan2_k<<<1, 512, 0, stream>>>(bsum, nb);
    scan3_k<<<(N + 1 + NT - 1) / NT, NT, 0, stream>>>(rowptr, bsum, cnt, N, E);
    scatter_k<<<(E + NT - 1) / NT, NT, 0, stream>>>(srcp, dstp, cnt, srcs, E);

    // ---- layer 1: gather-aggregate x -> bufA, then in-place GEMM ----
    gather128_k<<<(N + 3) / 4, NT, 0, stream>>>(rowptr, srcs, dinv, x, bufA, N);
    gemm_k<128, true, true><<<(N + 127) / 128, NT, 0, stream>>>(bufA, W1, b1, bufA, N);

    // ---- layer 2: transform -> bufB, gather-aggregate -> out (+b2) ----
    gemm_k<64, false, false><<<(N + 255) / 256, NT, 0, stream>>>(bufA, W2, nullptr, bufB, N);
    gather64_k<<<(N + 3) / 4, NT, 0, stream>>>(rowptr, srcs, dinv, bufB, b2, out, N);
}

// Round 4
// 468.348 us; speedup vs baseline: 2.5679x; 1.2472x over previous
//
#include <hip/hip_runtime.h>
#include <hip/hip_fp16.h>

// ---------------------------------------------------------------------------
// 2-layer GCN (PyG GCNConv): deg^{-1/2} sym norm with self-loops.
// Round 4: fp16 pre-scaled gather operands.
//   xh[s] = fp16(x[s] * dinv[s])          (layer-1 gather payload, 2B/elem)
//   th[s] = fp16((h1 @ W2)[s] * dinv[s])  (layer-2 gather payload)
//   agg[d] = dinv[d] * ( sum_src xh[src] + xh[d] )   -> no per-edge dinv/mul
// CSR (dst-sorted src lists) built on device every launch (deterministic).
// ---------------------------------------------------------------------------

#define NT 256

// ---------------- CSR build ----------------

__global__ void zero_counts_k(int* __restrict__ c, int n) {
    int i = blockIdx.x * NT + threadIdx.x;
    if (i < n) c[i] = 0;
}

__global__ void deg_count_k(const int* __restrict__ dst, int* __restrict__ c, int e) {
    int i = blockIdx.x * NT + threadIdx.x;
    if (i < e) atomicAdd(&c[dst[i]], 1);
}

// exclusive scan of counts -> rowptr (3-phase); also emits dinv = rsqrt(cnt+1)
__global__ void scan1_k(const int* __restrict__ counts, int* __restrict__ rowptr,
                        int* __restrict__ bsum, float* __restrict__ dinv, int n) {
    __shared__ int s[NT];
    int tid = threadIdx.x, i = blockIdx.x * NT + tid;
    int v = (i < n) ? counts[i] : 0;
    if (i < n) dinv[i] = rsqrtf((float)(v + 1));  // +1 self-loop
    s[tid] = v;
    __syncthreads();
    for (int off = 1; off < NT; off <<= 1) {
        int t = (tid >= off) ? s[tid - off] : 0;
        __syncthreads();
        if (tid >= off) s[tid] += t;
        __syncthreads();
    }
    if (i < n) rowptr[i] = s[tid] - v;  // exclusive within block
    if (tid == NT - 1) bsum[blockIdx.x] = s[tid];
}

__global__ void scan2_k(int* __restrict__ bsum, int nb) {
    __shared__ int s[512];
    __shared__ int carry;
    int tid = threadIdx.x;
    if (tid == 0) carry = 0;
    __syncthreads();
    for (int base = 0; base < nb; base += 512) {
        int i = base + tid;
        int v = (i < nb) ? bsum[i] : 0;
        s[tid] = v;
        __syncthreads();
        for (int off = 1; off < 512; off <<= 1) {
            int t = (tid >= off) ? s[tid - off] : 0;
            __syncthreads();
            if (tid >= off) s[tid] += t;
            __syncthreads();
        }
        int tot = s[511];
        if (i < nb) bsum[i] = s[tid] - v + carry;
        __syncthreads();
        if (tid == 0) carry += tot;
        __syncthreads();
    }
}

__global__ void scan3_k(int* __restrict__ rowptr, const int* __restrict__ bsum,
                        int* __restrict__ cursor, int n, int e) {
    int i = blockIdx.x * NT + threadIdx.x;
    if (i < n) {
        int r = rowptr[i] + bsum[i / NT];
        rowptr[i] = r;
        cursor[i] = r;
    } else if (i == n) {
        rowptr[n] = e;
    }
}

__global__ void scatter_k(const int* __restrict__ src, const int* __restrict__ dst,
                          int* __restrict__ cursor, int* __restrict__ srcs, int e) {
    int i = blockIdx.x * NT + threadIdx.x;
    if (i < e) {
        int pos = atomicAdd(&cursor[dst[i]], 1);
        srcs[pos] = src[i];
    }
}

// ---------------- fp16 pre-scale convert: xh = fp16(x * dinv[row]) --------
// one thread per 8 floats (row-aligned since 128 % 8 == 0)
__global__ void conv1_k(const float* __restrict__ x, const float* __restrict__ dinv,
                        int4* __restrict__ xh, int total /* = N*16 */) {
    int idx = blockIdx.x * NT + threadIdx.x;
    if (idx >= total) return;
    int node = idx >> 4;  // 16 chunks of 8 per 128-row
    float dn = dinv[node];
    const float4* xp = reinterpret_cast<const float4*>(x) + (size_t)idx * 2;
    float4 a = xp[0], b = xp[1];
    __half2 h[4];
    h[0] = __floats2half2_rn(a.x * dn, a.y * dn);
    h[1] = __floats2half2_rn(a.z * dn, a.w * dn);
    h[2] = __floats2half2_rn(b.x * dn, b.y * dn);
    h[3] = __floats2half2_rn(b.z * dn, b.w * dn);
    xh[idx] = *reinterpret_cast<int4*>(h);
}

// ---------------- gather aggregation (one wave per node) ----------------

// D=128 fp16: lane covers half2 col pair; agg -> fp32 out (scaled by dinv[d])
__global__ __launch_bounds__(NT) void gather128_k(
    const int* __restrict__ rowptr, const int* __restrict__ srcs,
    const float* __restrict__ dinv, const __half2* __restrict__ xh,
    float* __restrict__ out, int n) {
    int node = blockIdx.x * (NT / 64) + (threadIdx.x >> 6);
    if (node >= n) return;
    int lane = threadIdx.x & 63;
    float2 acc = __half22float2(xh[(size_t)node * 64 + lane]);  // self-loop
    int e = rowptr[node], e1 = rowptr[node + 1];
    for (; e + 3 < e1; e += 4) {
        int s0 = srcs[e], s1 = srcs[e + 1], s2 = srcs[e + 2], s3 = srcs[e + 3];
        float2 f0 = __half22float2(xh[(size_t)s0 * 64 + lane]);
        float2 f1 = __half22float2(xh[(size_t)s1 * 64 + lane]);
        float2 f2 = __half22float2(xh[(size_t)s2 * 64 + lane]);
        float2 f3 = __half22float2(xh[(size_t)s3 * 64 + lane]);
        acc.x += (f0.x + f1.x) + (f2.x + f3.x);
        acc.y += (f0.y + f1.y) + (f2.y + f3.y);
    }
    for (; e < e1; ++e) {
        float2 f = __half22float2(xh[(size_t)srcs[e] * 64 + lane]);
        acc.x += f.x;
        acc.y += f.y;
    }
    float dn = dinv[node];
    *reinterpret_cast<float2*>(&out[(size_t)node * 128 + lane * 2]) =
        make_float2(acc.x * dn, acc.y * dn);
}

// D=64 fp16: lane covers one col; out = dinv[d]*acc + bias
__global__ __launch_bounds__(NT) void gather64_k(
    const int* __restrict__ rowptr, const int* __restrict__ srcs,
    const float* __restrict__ dinv, const __half* __restrict__ th,
    const float* __restrict__ bias, float* __restrict__ out, int n) {
    int node = blockIdx.x * (NT / 64) + (threadIdx.x >> 6);
    if (node >= n) return;
    int lane = threadIdx.x & 63;
    float acc = __half2float(th[(size_t)node * 64 + lane]);  // self-loop
    int e = rowptr[node], e1 = rowptr[node + 1];
    for (; e + 3 < e1; e += 4) {
        int s0 = srcs[e], s1 = srcs[e + 1], s2 = srcs[e + 2], s3 = srcs[e + 3];
        float a0 = __half2float(th[(size_t)s0 * 64 + lane]);
        float a1 = __half2float(th[(size_t)s1 * 64 + lane]);
        float a2 = __half2float(th[(size_t)s2 * 64 + lane]);
        float a3 = __half2float(th[(size_t)s3 * 64 + lane]);
        acc += (a0 + a1) + (a2 + a3);
    }
    for (; e < e1; ++e)
        acc += __half2float(th[(size_t)srcs[e] * 64 + lane]);
    out[(size_t)node * 64 + lane] = acc * dinv[node] + bias[lane];
}

// ---------------- dense GEMM (fp32 vector ALU, W in LDS) ----------------
// HOUT=false: writes fp32 C (optionally +bias, relu). Safe for A == C.
// HOUT=true : writes fp16 hout[row] = fp16(acc * dinv[row]).
template <int OC, bool RELU, bool BIAS, bool HOUT>
__global__ __launch_bounds__(NT) void gemm_k(
    const float* __restrict__ A, const float* __restrict__ W,
    const float* __restrict__ bias, float* __restrict__ C,
    const float* __restrict__ dinv, __half* __restrict__ hout, int nrows) {
    constexpr int TC  = 16;
    constexpr int TR  = 4;
    constexpr int NCG = OC / TC;
    constexpr int RPB = (NT / NCG) * TR;

    __shared__ float sW[128 * OC];
    for (int i = threadIdx.x; i < 128 * OC / 4; i += NT)
        reinterpret_cast<float4*>(sW)[i] = reinterpret_cast<const float4*>(W)[i];
    __syncthreads();

    const int cg   = threadIdx.x % NCG;
    const int rg   = threadIdx.x / NCG;
    const int row0 = blockIdx.x * RPB + rg * TR;

    float acc[TR][TC];
#pragma unroll
    for (int r = 0; r < TR; ++r)
#pragma unroll
        for (int c = 0; c < TC; ++c) acc[r][c] = 0.0f;

    for (int kc = 0; kc < 128; kc += 4) {
        float4 a[TR];
#pragma unroll
        for (int r = 0; r < TR; ++r) {
            int row = row0 + r;
            if (row >= nrows) row = nrows - 1;
            a[r] = *reinterpret_cast<const float4*>(&A[(long long)row * 128 + kc]);
        }
#pragma unroll
        for (int kk = 0; kk < 4; ++kk) {
            float w[TC];
#pragma unroll
            for (int j = 0; j < TC / 4; ++j) {
                float4 wv = *reinterpret_cast<const float4*>(
                    &sW[(kc + kk) * OC + cg * TC + j * 4]);
                w[j * 4 + 0] = wv.x; w[j * 4 + 1] = wv.y;
                w[j * 4 + 2] = wv.z; w[j * 4 + 3] = wv.w;
            }
#pragma unroll
            for (int r = 0; r < TR; ++r) {
                float av = (kk == 0) ? a[r].x : (kk == 1) ? a[r].y
                         : (kk == 2) ? a[r].z : a[r].w;
#pragma unroll
                for (int c = 0; c < TC; ++c) acc[r][c] += av * w[c];
            }
        }
    }

    __syncthreads();  // A==C safety

#pragma unroll
    for (int r = 0; r < TR; ++r) {
        int row = row0 + r;
        if (row < nrows) {
            if (HOUT) {
                float dn = dinv[row];
                __half2 hp[TC / 2];
#pragma unroll
                for (int j = 0; j < TC / 2; ++j)
                    hp[j] = __floats2half2_rn(acc[r][2 * j] * dn,
                                              acc[r][2 * j + 1] * dn);
#pragma unroll
                for (int j = 0; j < TC / 8; ++j)
                    *reinterpret_cast<int4*>(&hout[(size_t)row * OC + cg * TC + j * 8]) =
                        reinterpret_cast<int4*>(hp)[j];
            } else {
#pragma unroll
                for (int c = 0; c < TC; ++c) {
                    float v = acc[r][c];
                    if (BIAS) v += bias[cg * TC + c];
                    if (RELU) v = fmaxf(v, 0.0f);
                    acc[r][c] = v;
                }
#pragma unroll
                for (int j = 0; j < TC / 4; ++j) {
                    float4 v = make_float4(acc[r][j * 4 + 0], acc[r][j * 4 + 1],
                                           acc[r][j * 4 + 2], acc[r][j * 4 + 3]);
                    *reinterpret_cast<float4*>(
                        &C[(long long)row * OC + cg * TC + j * 4]) = v;
                }
            }
        }
    }
}

// ---------------------------------------------------------------------------

extern "C" void kernel_launch(void* const* d_in, const int* in_sizes, int n_in,
                              void* d_out, int out_size, void* d_ws, size_t ws_size,
                              hipStream_t stream) {
    const float* x   = (const float*)d_in[0];
    const int*   ei  = (const int*)d_in[1];
    const float* W1  = (const float*)d_in[2];
    const float* b1  = (const float*)d_in[3];
    const float* W2  = (const float*)d_in[4];
    const float* b2  = (const float*)d_in[5];
    float*       out = (float*)d_out;

    const int N = in_sizes[0] / 128;
    const int E = in_sizes[1] / 2;
    const int* srcp = ei;      // edge_index[0]
    const int* dstp = ei + E;  // edge_index[1]

    const int nb = (N + NT - 1) / NT;

    // workspace (512B-aligned):
    //   dinv[N] | cnt[N] | rowptr[N+1] | bsum[nb] | srcs[E]
    //   | xh[N*128 fp16]  (later reused as th[N*64 fp16])
    //   | bufA[N*128 fp32]                               (~84.4 MB)
    char* ws = (char*)d_ws;
    size_t off = 0;
    auto alloc = [&](size_t bytes) {
        char* p = ws + off;
        off = (off + bytes + 511) & ~(size_t)511;
        return p;
    };
    float*  dinv   = (float*)alloc((size_t)N * 4);
    int*    cnt    = (int*)alloc((size_t)N * 4);   // counts, then scatter cursor
    int*    rowptr = (int*)alloc((size_t)(N + 1) * 4);
    int*    bsum   = (int*)alloc((size_t)nb * 4);
    int*    srcs   = (int*)alloc((size_t)E * 4);
    __half* xh     = (__half*)alloc((size_t)N * 128 * 2);  // also th (N*64*2)
    float*  bufA   = (float*)alloc((size_t)N * 128 * 4);

    // ---- CSR build + norm ----
    zero_counts_k<<<nb, NT, 0, stream>>>(cnt, N);
    deg_count_k<<<(E + NT - 1) / NT, NT, 0, stream>>>(dstp, cnt, E);
    scan1_k<<<nb, NT, 0, stream>>>(cnt, rowptr, bsum, dinv, N);
    scan2_k<<<1, 512, 0, stream>>>(bsum, nb);
    scan3_k<<<(N + 1 + NT - 1) / NT, NT, 0, stream>>>(rowptr, bsum, cnt, N, E);
    scatter_k<<<(E + NT - 1) / NT, NT, 0, stream>>>(srcp, dstp, cnt, srcs, E);

    // ---- layer 1 ----
    conv1_k<<<(N * 16 + NT - 1) / NT, NT, 0, stream>>>(x, dinv, (int4*)xh, N * 16);
    gather128_k<<<(N + 3) / 4, NT, 0, stream>>>(rowptr, srcs, dinv,
                                                (const __half2*)xh, bufA, N);
    gemm_k<128, true, true, false><<<(N + 127) / 128, NT, 0, stream>>>(
        bufA, W1, b1, bufA, nullptr, nullptr, N);

    // ---- layer 2 ----  (th overlays xh region; xh dead after gather128)
    __half* th = xh;
    gemm_k<64, false, false, true><<<(N + 255) / 256, NT, 0, stream>>>(
        bufA, W2, nullptr, nullptr, dinv, th, N);
    gather64_k<<<(N + 3) / 4, NT, 0, stream>>>(rowptr, srcs, dinv, th, b2, out, N);
}

// Round 5
// 416.663 us; speedup vs baseline: 2.8864x; 1.1240x over previous
//
#include <hip/hip_runtime.h>
#include <hip/hip_fp16.h>

// ---------------------------------------------------------------------------
// 2-layer GCN (PyG GCNConv): deg^{-1/2} sym norm with self-loops.
// Round 5: XCD-localized CSR scatter. Round-4 profile showed scatter_k at
// ~125 us, WRITE_SIZE ~105 MB for a 6.4 MB payload (64B-line amplification:
// each srcs line written from ~8 XCDs). Fix: blocks with blockIdx%8==q only
// scatter edges whose dst is in node-region q, so each srcs region is written
// by one XCD's L2 only (lines merge before write-back). Costs an 8x re-read
// of dst (coalesced, L3-served), saves ~100 MB of random write traffic.
// ---------------------------------------------------------------------------

#define NT 256

// ---------------- CSR build ----------------

__global__ void zero_counts_k(int* __restrict__ c, int n) {
    int i = blockIdx.x * NT + threadIdx.x;
    if (i < n) c[i] = 0;
}

__global__ void deg_count_k(const int* __restrict__ dst, int* __restrict__ c, int e) {
    int i = blockIdx.x * NT + threadIdx.x;
    if (i < e) atomicAdd(&c[dst[i]], 1);
}

// exclusive scan of counts -> rowptr (3-phase); also emits dinv = rsqrt(cnt+1)
__global__ void scan1_k(const int* __restrict__ counts, int* __restrict__ rowptr,
                        int* __restrict__ bsum, float* __restrict__ dinv, int n) {
    __shared__ int s[NT];
    int tid = threadIdx.x, i = blockIdx.x * NT + tid;
    int v = (i < n) ? counts[i] : 0;
    if (i < n) dinv[i] = rsqrtf((float)(v + 1));  // +1 self-loop
    s[tid] = v;
    __syncthreads();
    for (int off = 1; off < NT; off <<= 1) {
        int t = (tid >= off) ? s[tid - off] : 0;
        __syncthreads();
        if (tid >= off) s[tid] += t;
        __syncthreads();
    }
    if (i < n) rowptr[i] = s[tid] - v;  // exclusive within block
    if (tid == NT - 1) bsum[blockIdx.x] = s[tid];
}

__global__ void scan2_k(int* __restrict__ bsum, int nb) {
    __shared__ int s[512];
    __shared__ int carry;
    int tid = threadIdx.x;
    if (tid == 0) carry = 0;
    __syncthreads();
    for (int base = 0; base < nb; base += 512) {
        int i = base + tid;
        int v = (i < nb) ? bsum[i] : 0;
        s[tid] = v;
        __syncthreads();
        for (int off = 1; off < 512; off <<= 1) {
            int t = (tid >= off) ? s[tid - off] : 0;
            __syncthreads();
            if (tid >= off) s[tid] += t;
            __syncthreads();
        }
        int tot = s[511];
        if (i < nb) bsum[i] = s[tid] - v + carry;
        __syncthreads();
        if (tid == 0) carry += tot;
        __syncthreads();
    }
}

__global__ void scan3_k(int* __restrict__ rowptr, const int* __restrict__ bsum,
                        int* __restrict__ cursor, int n, int e) {
    int i = blockIdx.x * NT + threadIdx.x;
    if (i < n) {
        int r = rowptr[i] + bsum[i / NT];
        rowptr[i] = r;
        cursor[i] = r;
    } else if (i == n) {
        rowptr[n] = e;
    }
}

// XCD-localized scatter: block handles edge chunk (blockIdx>>3), but only
// edges whose dst lies in node-region (blockIdx&7). With round-robin
// block->XCD dispatch, each srcs region is written by exactly one XCD.
__global__ __launch_bounds__(NT) void scatter_xcd_k(
    const int* __restrict__ src, const int* __restrict__ dst,
    int* __restrict__ cursor, int* __restrict__ srcs,
    int e, int rpx, int csz) {
    int q  = blockIdx.x & 7;
    int ch = blockIdx.x >> 3;
    int lo = q * rpx, hi = lo + rpx;
    int e0 = ch * csz;
    int e1 = min(e, e0 + csz);
    for (int i = e0 + (int)threadIdx.x; i < e1; i += NT) {
        int d = dst[i];
        if (d >= lo && d < hi) {
            int pos = atomicAdd(&cursor[d], 1);
            srcs[pos] = src[i];
        }
    }
}

// ---------------- fp16 pre-scale convert: xh = fp16(x * dinv[row]) --------
__global__ void conv1_k(const float* __restrict__ x, const float* __restrict__ dinv,
                        int4* __restrict__ xh, int total /* = N*16 */) {
    int idx = blockIdx.x * NT + threadIdx.x;
    if (idx >= total) return;
    int node = idx >> 4;  // 16 chunks of 8 per 128-row
    float dn = dinv[node];
    const float4* xp = reinterpret_cast<const float4*>(x) + (size_t)idx * 2;
    float4 a = xp[0], b = xp[1];
    __half2 h[4];
    h[0] = __floats2half2_rn(a.x * dn, a.y * dn);
    h[1] = __floats2half2_rn(a.z * dn, a.w * dn);
    h[2] = __floats2half2_rn(b.x * dn, b.y * dn);
    h[3] = __floats2half2_rn(b.z * dn, b.w * dn);
    xh[idx] = *reinterpret_cast<int4*>(h);
}

// ---------------- gather aggregation (one wave per node) ----------------

// D=128 fp16: lane covers half2 col pair; agg -> fp32 out (scaled by dinv[d])
__global__ __launch_bounds__(NT) void gather128_k(
    const int* __restrict__ rowptr, const int* __restrict__ srcs,
    const float* __restrict__ dinv, const __half2* __restrict__ xh,
    float* __restrict__ out, int n) {
    int node = blockIdx.x * (NT / 64) + (threadIdx.x >> 6);
    if (node >= n) return;
    int lane = threadIdx.x & 63;
    float2 acc = __half22float2(xh[(size_t)node * 64 + lane]);  // self-loop
    int e = rowptr[node], e1 = rowptr[node + 1];
    for (; e + 3 < e1; e += 4) {
        int s0 = srcs[e], s1 = srcs[e + 1], s2 = srcs[e + 2], s3 = srcs[e + 3];
        float2 f0 = __half22float2(xh[(size_t)s0 * 64 + lane]);
        float2 f1 = __half22float2(xh[(size_t)s1 * 64 + lane]);
        float2 f2 = __half22float2(xh[(size_t)s2 * 64 + lane]);
        float2 f3 = __half22float2(xh[(size_t)s3 * 64 + lane]);
        acc.x += (f0.x + f1.x) + (f2.x + f3.x);
        acc.y += (f0.y + f1.y) + (f2.y + f3.y);
    }
    for (; e < e1; ++e) {
        float2 f = __half22float2(xh[(size_t)srcs[e] * 64 + lane]);
        acc.x += f.x;
        acc.y += f.y;
    }
    float dn = dinv[node];
    *reinterpret_cast<float2*>(&out[(size_t)node * 128 + lane * 2]) =
        make_float2(acc.x * dn, acc.y * dn);
}

// D=64 fp16: lane covers one col; out = dinv[d]*acc + bias
__global__ __launch_bounds__(NT) void gather64_k(
    const int* __restrict__ rowptr, const int* __restrict__ srcs,
    const float* __restrict__ dinv, const __half* __restrict__ th,
    const float* __restrict__ bias, float* __restrict__ out, int n) {
    int node = blockIdx.x * (NT / 64) + (threadIdx.x >> 6);
    if (node >= n) return;
    int lane = threadIdx.x & 63;
    float acc = __half2float(th[(size_t)node * 64 + lane]);  // self-loop
    int e = rowptr[node], e1 = rowptr[node + 1];
    for (; e + 3 < e1; e += 4) {
        int s0 = srcs[e], s1 = srcs[e + 1], s2 = srcs[e + 2], s3 = srcs[e + 3];
        float a0 = __half2float(th[(size_t)s0 * 64 + lane]);
        float a1 = __half2float(th[(size_t)s1 * 64 + lane]);
        float a2 = __half2float(th[(size_t)s2 * 64 + lane]);
        float a3 = __half2float(th[(size_t)s3 * 64 + lane]);
        acc += (a0 + a1) + (a2 + a3);
    }
    for (; e < e1; ++e)
        acc += __half2float(th[(size_t)srcs[e] * 64 + lane]);
    out[(size_t)node * 64 + lane] = acc * dinv[node] + bias[lane];
}

// ---------------- dense GEMM (fp32 vector ALU, W in LDS) ----------------
// HOUT=false: writes fp32 C (optionally +bias, relu). Safe for A == C.
// HOUT=true : writes fp16 hout[row] = fp16(acc * dinv[row]).
template <int OC, bool RELU, bool BIAS, bool HOUT>
__global__ __launch_bounds__(NT) void gemm_k(
    const float* __restrict__ A, const float* __restrict__ W,
    const float* __restrict__ bias, float* __restrict__ C,
    const float* __restrict__ dinv, __half* __restrict__ hout, int nrows) {
    constexpr int TC  = 16;
    constexpr int TR  = 4;
    constexpr int NCG = OC / TC;
    constexpr int RPB = (NT / NCG) * TR;

    __shared__ float sW[128 * OC];
    for (int i = threadIdx.x; i < 128 * OC / 4; i += NT)
        reinterpret_cast<float4*>(sW)[i] = reinterpret_cast<const float4*>(W)[i];
    __syncthreads();

    const int cg   = threadIdx.x % NCG;
    const int rg   = threadIdx.x / NCG;
    const int row0 = blockIdx.x * RPB + rg * TR;

    float acc[TR][TC];
#pragma unroll
    for (int r = 0; r < TR; ++r)
#pragma unroll
        for (int c = 0; c < TC; ++c) acc[r][c] = 0.0f;

    for (int kc = 0; kc < 128; kc += 4) {
        float4 a[TR];
#pragma unroll
        for (int r = 0; r < TR; ++r) {
            int row = row0 + r;
            if (row >= nrows) row = nrows - 1;
            a[r] = *reinterpret_cast<const float4*>(&A[(long long)row * 128 + kc]);
        }
#pragma unroll
        for (int kk = 0; kk < 4; ++kk) {
            float w[TC];
#pragma unroll
            for (int j = 0; j < TC / 4; ++j) {
                float4 wv = *reinterpret_cast<const float4*>(
                    &sW[(kc + kk) * OC + cg * TC + j * 4]);
                w[j * 4 + 0] = wv.x; w[j * 4 + 1] = wv.y;
                w[j * 4 + 2] = wv.z; w[j * 4 + 3] = wv.w;
            }
#pragma unroll
            for (int r = 0; r < TR; ++r) {
                float av = (kk == 0) ? a[r].x : (kk == 1) ? a[r].y
                         : (kk == 2) ? a[r].z : a[r].w;
#pragma unroll
                for (int c = 0; c < TC; ++c) acc[r][c] += av * w[c];
            }
        }
    }

    __syncthreads();  // A==C safety

#pragma unroll
    for (int r = 0; r < TR; ++r) {
        int row = row0 + r;
        if (row < nrows) {
            if (HOUT) {
                float dn = dinv[row];
                __half2 hp[TC / 2];
#pragma unroll
                for (int j = 0; j < TC / 2; ++j)
                    hp[j] = __floats2half2_rn(acc[r][2 * j] * dn,
                                              acc[r][2 * j + 1] * dn);
#pragma unroll
                for (int j = 0; j < TC / 8; ++j)
                    *reinterpret_cast<int4*>(&hout[(size_t)row * OC + cg * TC + j * 8]) =
                        reinterpret_cast<int4*>(hp)[j];
            } else {
#pragma unroll
                for (int c = 0; c < TC; ++c) {
                    float v = acc[r][c];
                    if (BIAS) v += bias[cg * TC + c];
                    if (RELU) v = fmaxf(v, 0.0f);
                    acc[r][c] = v;
                }
#pragma unroll
                for (int j = 0; j < TC / 4; ++j) {
                    float4 v = make_float4(acc[r][j * 4 + 0], acc[r][j * 4 + 1],
                                           acc[r][j * 4 + 2], acc[r][j * 4 + 3]);
                    *reinterpret_cast<float4*>(
                        &C[(long long)row * OC + cg * TC + j * 4]) = v;
                }
            }
        }
    }
}

// ---------------------------------------------------------------------------

extern "C" void kernel_launch(void* const* d_in, const int* in_sizes, int n_in,
                              void* d_out, int out_size, void* d_ws, size_t ws_size,
                              hipStream_t stream) {
    const float* x   = (const float*)d_in[0];
    const int*   ei  = (const int*)d_in[1];
    const float* W1  = (const float*)d_in[2];
    const float* b1  = (const float*)d_in[3];
    const float* W2  = (const float*)d_in[4];
    const float* b2  = (const float*)d_in[5];
    float*       out = (float*)d_out;

    const int N = in_sizes[0] / 128;
    const int E = in_sizes[1] / 2;
    const int* srcp = ei;      // edge_index[0]
    const int* dstp = ei + E;  // edge_index[1]

    const int nb = (N + NT - 1) / NT;

    // workspace (512B-aligned):
    //   dinv[N] | cnt[N] | rowptr[N+1] | bsum[nb] | srcs[E]
    //   | xh[N*128 fp16] (reused as th) | bufA[N*128 fp32]   (~84.4 MB)
    char* ws = (char*)d_ws;
    size_t off = 0;
    auto alloc = [&](size_t bytes) {
        char* p = ws + off;
        off = (off + bytes + 511) & ~(size_t)511;
        return p;
    };
    float*  dinv   = (float*)alloc((size_t)N * 4);
    int*    cnt    = (int*)alloc((size_t)N * 4);   // counts, then scatter cursor
    int*    rowptr = (int*)alloc((size_t)(N + 1) * 4);
    int*    bsum   = (int*)alloc((size_t)nb * 4);
    int*    srcs   = (int*)alloc((size_t)E * 4);
    __half* xh     = (__half*)alloc((size_t)N * 128 * 2);  // also th (N*64*2)
    float*  bufA   = (float*)alloc((size_t)N * 128 * 4);

    // ---- CSR build + norm ----
    zero_counts_k<<<nb, NT, 0, stream>>>(cnt, N);
    deg_count_k<<<(E + NT - 1) / NT, NT, 0, stream>>>(dstp, cnt, E);
    scan1_k<<<nb, NT, 0, stream>>>(cnt, rowptr, bsum, dinv, N);
    scan2_k<<<1, 512, 0, stream>>>(bsum, nb);
    scan3_k<<<(N + 1 + NT - 1) / NT, NT, 0, stream>>>(rowptr, bsum, cnt, N, E);
    {
        const int CH  = 2048;                  // edge chunks
        const int csz = (E + CH - 1) / CH;     // edges per chunk
        const int rpx = (N + 7) / 8;           // nodes per XCD region
        scatter_xcd_k<<<8 * CH, NT, 0, stream>>>(srcp, dstp, cnt, srcs, E, rpx, csz);
    }

    // ---- layer 1 ----
    conv1_k<<<(N * 16 + NT - 1) / NT, NT, 0, stream>>>(x, dinv, (int4*)xh, N * 16);
    gather128_k<<<(N + 3) / 4, NT, 0, stream>>>(rowptr, srcs, dinv,
                                                (const __half2*)xh, bufA, N);
    gemm_k<128, true, true, false><<<(N + 127) / 128, NT, 0, stream>>>(
        bufA, W1, b1, bufA, nullptr, nullptr, N);

    // ---- layer 2 ----  (th overlays xh region; xh dead after gather128)
    __half* th = xh;
    gemm_k<64, false, false, true><<<(N + 255) / 256, NT, 0, stream>>>(
        bufA, W2, nullptr, nullptr, dinv, th, N);
    gather64_k<<<(N + 3) / 4, NT, 0, stream>>>(rowptr, srcs, dinv, th, b2, out, N);
}

// Round 6
// 350.971 us; speedup vs baseline: 3.4267x; 1.1872x over previous
//
#include <hip/hip_runtime.h>
#include <hip/hip_fp16.h>

// ---------------------------------------------------------------------------
// 2-layer GCN (PyG GCNConv): deg^{-1/2} sym norm with self-loops.
// Round 6: MFMA fp16 GEMMs with register-resident B (no LDS, no barriers).
//   conv1:    xh   = fp16(x * dinv)                  [N x 128]
//   gather128:aggH = fp16(dinv[d] * (sum xh[src] + xh[d]))
//   mgemm1:   h1   = fp16(relu(aggH @ W1 + b1))      (MFMA 16x16x32_f16)
//   mgemm2:   th   = fp16((h1 @ W2) * dinv)          (MFMA)
//   gather64: out  = dinv[d]*(sum th[src] + th[d]) + b2   (fp32)
// CSR built on device per launch; scatter is XCD-localized (round 5).
// ---------------------------------------------------------------------------

#define NT 256

typedef _Float16 half8 __attribute__((ext_vector_type(8)));
typedef float floatx4 __attribute__((ext_vector_type(4)));

// ---------------- CSR build ----------------

__global__ void zero_counts_k(int* __restrict__ c, int n) {
    int i = blockIdx.x * NT + threadIdx.x;
    if (i < n) c[i] = 0;
}

__global__ void deg_count_k(const int* __restrict__ dst, int* __restrict__ c, int e) {
    int i = blockIdx.x * NT + threadIdx.x;
    if (i < e) atomicAdd(&c[dst[i]], 1);
}

// exclusive scan of counts -> rowptr (3-phase); also emits dinv = rsqrt(cnt+1)
__global__ void scan1_k(const int* __restrict__ counts, int* __restrict__ rowptr,
                        int* __restrict__ bsum, float* __restrict__ dinv, int n) {
    __shared__ int s[NT];
    int tid = threadIdx.x, i = blockIdx.x * NT + tid;
    int v = (i < n) ? counts[i] : 0;
    if (i < n) dinv[i] = rsqrtf((float)(v + 1));  // +1 self-loop
    s[tid] = v;
    __syncthreads();
    for (int off = 1; off < NT; off <<= 1) {
        int t = (tid >= off) ? s[tid - off] : 0;
        __syncthreads();
        if (tid >= off) s[tid] += t;
        __syncthreads();
    }
    if (i < n) rowptr[i] = s[tid] - v;  // exclusive within block
    if (tid == NT - 1) bsum[blockIdx.x] = s[tid];
}

__global__ void scan2_k(int* __restrict__ bsum, int nb) {
    __shared__ int s[512];
    __shared__ int carry;
    int tid = threadIdx.x;
    if (tid == 0) carry = 0;
    __syncthreads();
    for (int base = 0; base < nb; base += 512) {
        int i = base + tid;
        int v = (i < nb) ? bsum[i] : 0;
        s[tid] = v;
        __syncthreads();
        for (int off = 1; off < 512; off <<= 1) {
            int t = (tid >= off) ? s[tid - off] : 0;
            __syncthreads();
            if (tid >= off) s[tid] += t;
            __syncthreads();
        }
        int tot = s[511];
        if (i < nb) bsum[i] = s[tid] - v + carry;
        __syncthreads();
        if (tid == 0) carry += tot;
        __syncthreads();
    }
}

__global__ void scan3_k(int* __restrict__ rowptr, const int* __restrict__ bsum,
                        int* __restrict__ cursor, int n, int e) {
    int i = blockIdx.x * NT + threadIdx.x;
    if (i < n) {
        int r = rowptr[i] + bsum[i / NT];
        rowptr[i] = r;
        cursor[i] = r;
    } else if (i == n) {
        rowptr[n] = e;
    }
}

// XCD-localized scatter (round 5): block (blockIdx&7) only scatters edges
// whose dst is in node-region q -> each srcs region written by one XCD's L2.
__global__ __launch_bounds__(NT) void scatter_xcd_k(
    const int* __restrict__ src, const int* __restrict__ dst,
    int* __restrict__ cursor, int* __restrict__ srcs,
    int e, int rpx, int csz) {
    int q  = blockIdx.x & 7;
    int ch = blockIdx.x >> 3;
    int lo = q * rpx, hi = lo + rpx;
    int e0 = ch * csz;
    int e1 = min(e, e0 + csz);
    for (int i = e0 + (int)threadIdx.x; i < e1; i += NT) {
        int d = dst[i];
        if (d >= lo && d < hi) {
            int pos = atomicAdd(&cursor[d], 1);
            srcs[pos] = src[i];
        }
    }
}

// ---------------- fp16 pre-scale convert: xh = fp16(x * dinv[row]) --------
__global__ void conv1_k(const float* __restrict__ x, const float* __restrict__ dinv,
                        int4* __restrict__ xh, int total /* = N*16 */) {
    int idx = blockIdx.x * NT + threadIdx.x;
    if (idx >= total) return;
    int node = idx >> 4;  // 16 chunks of 8 per 128-row
    float dn = dinv[node];
    const float4* xp = reinterpret_cast<const float4*>(x) + (size_t)idx * 2;
    float4 a = xp[0], b = xp[1];
    __half2 h[4];
    h[0] = __floats2half2_rn(a.x * dn, a.y * dn);
    h[1] = __floats2half2_rn(a.z * dn, a.w * dn);
    h[2] = __floats2half2_rn(b.x * dn, b.y * dn);
    h[3] = __floats2half2_rn(b.z * dn, b.w * dn);
    xh[idx] = *reinterpret_cast<int4*>(h);
}

// ---------------- gather aggregation (one wave per node) ----------------

// D=128 fp16 in, fp16 out: aggH[d] = fp16(dinv[d] * (sum xh[src] + xh[d]))
__global__ __launch_bounds__(NT) void gather128_k(
    const int* __restrict__ rowptr, const int* __restrict__ srcs,
    const float* __restrict__ dinv, const __half2* __restrict__ xh,
    __half2* __restrict__ aggH, int n) {
    int node = blockIdx.x * (NT / 64) + (threadIdx.x >> 6);
    if (node >= n) return;
    int lane = threadIdx.x & 63;
    float2 acc = __half22float2(xh[(size_t)node * 64 + lane]);  // self-loop
    int e = rowptr[node], e1 = rowptr[node + 1];
    for (; e + 3 < e1; e += 4) {
        int s0 = srcs[e], s1 = srcs[e + 1], s2 = srcs[e + 2], s3 = srcs[e + 3];
        float2 f0 = __half22float2(xh[(size_t)s0 * 64 + lane]);
        float2 f1 = __half22float2(xh[(size_t)s1 * 64 + lane]);
        float2 f2 = __half22float2(xh[(size_t)s2 * 64 + lane]);
        float2 f3 = __half22float2(xh[(size_t)s3 * 64 + lane]);
        acc.x += (f0.x + f1.x) + (f2.x + f3.x);
        acc.y += (f0.y + f1.y) + (f2.y + f3.y);
    }
    for (; e < e1; ++e) {
        float2 f = __half22float2(xh[(size_t)srcs[e] * 64 + lane]);
        acc.x += f.x;
        acc.y += f.y;
    }
    float dn = dinv[node];
    aggH[(size_t)node * 64 + lane] = __floats2half2_rn(acc.x * dn, acc.y * dn);
}

// D=64 fp16: out = dinv[d]*acc + bias (fp32 final output)
__global__ __launch_bounds__(NT) void gather64_k(
    const int* __restrict__ rowptr, const int* __restrict__ srcs,
    const float* __restrict__ dinv, const __half* __restrict__ th,
    const float* __restrict__ bias, float* __restrict__ out, int n) {
    int node = blockIdx.x * (NT / 64) + (threadIdx.x >> 6);
    if (node >= n) return;
    int lane = threadIdx.x & 63;
    float acc = __half2float(th[(size_t)node * 64 + lane]);  // self-loop
    int e = rowptr[node], e1 = rowptr[node + 1];
    for (; e + 3 < e1; e += 4) {
        int s0 = srcs[e], s1 = srcs[e + 1], s2 = srcs[e + 2], s3 = srcs[e + 3];
        float a0 = __half2float(th[(size_t)s0 * 64 + lane]);
        float a1 = __half2float(th[(size_t)s1 * 64 + lane]);
        float a2 = __half2float(th[(size_t)s2 * 64 + lane]);
        float a3 = __half2float(th[(size_t)s3 * 64 + lane]);
        acc += (a0 + a1) + (a2 + a3);
    }
    for (; e < e1; ++e)
        acc += __half2float(th[(size_t)srcs[e] * 64 + lane]);
    out[(size_t)node * 64 + lane] = acc * dinv[node] + bias[lane];
}

// ---------------- MFMA fp16 GEMM, register-resident B ----------------
// out[row, n] = f( A[row,:128] @ W[:128, n] )  with A fp16, W fp32 (converted
// in-register), out fp16. No LDS, no barriers: each wave holds its full B
// operand (16*NREP cols x K=128) in 16*NREP VGPRs, loaded once.
// mfma_f32_16x16x32_f16 layouts: A lane l: row=l&15, k=(l>>4)*8+j.
// B lane l: col=l&15, k=(l>>4)*8+j. C/D lane l: col=l&15, row=(l>>4)*4+r.
// Block = 4 waves, wave w covers cols [w*16*NREP, (w+1)*16*NREP).
// Each block iteration covers 64 rows (M_rep=4).
template <int OC, bool RELU, bool BIAS, bool SCALE_DINV>
__global__ __launch_bounds__(NT) void mgemm_k(
    const __half* __restrict__ A, const float* __restrict__ W,
    const float* __restrict__ bias, const float* __restrict__ dinv,
    __half* __restrict__ out, int nrows) {
    constexpr int NREP = OC / 64;  // n-tiles per wave (2 for OC=128, 1 for 64)

    const int wid  = threadIdx.x >> 6;
    const int lane = threadIdx.x & 63;
    const int lrow = lane & 15;   // A-row / B-col / C-col within tile
    const int kgrp = lane >> 4;   // 0..3
    const int nbase = wid * 16 * NREP;

    // ---- B fragments (register-resident, loaded once) ----
    half8 bf[NREP][4];
    float bv[NREP];
#pragma unroll
    for (int nt = 0; nt < NREP; ++nt) {
        int col = nbase + nt * 16 + lrow;
#pragma unroll
        for (int kk = 0; kk < 4; ++kk) {
#pragma unroll
            for (int j = 0; j < 8; ++j) {
                int k = kk * 32 + kgrp * 8 + j;
                bf[nt][kk][j] = (_Float16)W[(size_t)k * OC + col];
            }
        }
        bv[nt] = BIAS ? bias[col] : 0.0f;
    }

    const int m0 = blockIdx.x * 64;

    floatx4 acc[4][NREP];
#pragma unroll
    for (int mt = 0; mt < 4; ++mt)
#pragma unroll
        for (int nt = 0; nt < NREP; ++nt)
            acc[mt][nt] = floatx4{0.f, 0.f, 0.f, 0.f};

#pragma unroll
    for (int kk = 0; kk < 4; ++kk) {
        half8 af[4];
#pragma unroll
        for (int mt = 0; mt < 4; ++mt) {
            int row = m0 + mt * 16 + lrow;
            if (row >= nrows) row = nrows - 1;  // clamp; stores are guarded
            af[mt] = *reinterpret_cast<const half8*>(
                &A[(size_t)row * 128 + kk * 32 + kgrp * 8]);
        }
#pragma unroll
        for (int mt = 0; mt < 4; ++mt)
#pragma unroll
            for (int nt = 0; nt < NREP; ++nt)
                acc[mt][nt] = __builtin_amdgcn_mfma_f32_16x16x32_f16(
                    af[mt], bf[nt][kk], acc[mt][nt], 0, 0, 0);
    }

    // ---- epilogue ----
#pragma unroll
    for (int mt = 0; mt < 4; ++mt) {
#pragma unroll
        for (int r = 0; r < 4; ++r) {
            int row = m0 + mt * 16 + kgrp * 4 + r;
            if (row < nrows) {
                float dn = SCALE_DINV ? dinv[row] : 1.0f;
#pragma unroll
                for (int nt = 0; nt < NREP; ++nt) {
                    float v = acc[mt][nt][r];
                    if (BIAS) v += bv[nt];
                    if (RELU) v = fmaxf(v, 0.0f);
                    if (SCALE_DINV) v *= dn;
                    out[(size_t)row * OC + nbase + nt * 16 + lrow] = __float2half(v);
                }
            }
        }
    }
}

// ---------------------------------------------------------------------------

extern "C" void kernel_launch(void* const* d_in, const int* in_sizes, int n_in,
                              void* d_out, int out_size, void* d_ws, size_t ws_size,
                              hipStream_t stream) {
    const float* x   = (const float*)d_in[0];
    const int*   ei  = (const int*)d_in[1];
    const float* W1  = (const float*)d_in[2];
    const float* b1  = (const float*)d_in[3];
    const float* W2  = (const float*)d_in[4];
    const float* b2  = (const float*)d_in[5];
    float*       out = (float*)d_out;

    const int N = in_sizes[0] / 128;
    const int E = in_sizes[1] / 2;
    const int* srcp = ei;      // edge_index[0]
    const int* dstp = ei + E;  // edge_index[1]

    const int nb = (N + NT - 1) / NT;

    // workspace (512B-aligned), ~59 MB:
    //   dinv[N] | cnt[N] | rowptr[N+1] | bsum[nb] | srcs[E]
    //   | regA[N*128 fp16] (xh, then h1) | regB[N*128 fp16] (aggH, then th)
    char* ws = (char*)d_ws;
    size_t off = 0;
    auto alloc = [&](size_t bytes) {
        char* p = ws + off;
        off = (off + bytes + 511) & ~(size_t)511;
        return p;
    };
    float*  dinv   = (float*)alloc((size_t)N * 4);
    int*    cnt    = (int*)alloc((size_t)N * 4);   // counts, then scatter cursor
    int*    rowptr = (int*)alloc((size_t)(N + 1) * 4);
    int*    bsum   = (int*)alloc((size_t)nb * 4);
    int*    srcs   = (int*)alloc((size_t)E * 4);
    __half* regA   = (__half*)alloc((size_t)N * 128 * 2);
    __half* regB   = (__half*)alloc((size_t)N * 128 * 2);

    // ---- CSR build + norm ----
    zero_counts_k<<<nb, NT, 0, stream>>>(cnt, N);
    deg_count_k<<<(E + NT - 1) / NT, NT, 0, stream>>>(dstp, cnt, E);
    scan1_k<<<nb, NT, 0, stream>>>(cnt, rowptr, bsum, dinv, N);
    scan2_k<<<1, 512, 0, stream>>>(bsum, nb);
    scan3_k<<<(N + 1 + NT - 1) / NT, NT, 0, stream>>>(rowptr, bsum, cnt, N, E);
    {
        const int CH  = 2048;               // edge chunks
        const int csz = (E + CH - 1) / CH;  // edges per chunk
        const int rpx = (N + 7) / 8;        // nodes per XCD region
        scatter_xcd_k<<<8 * CH, NT, 0, stream>>>(srcp, dstp, cnt, srcs, E, rpx, csz);
    }

    // ---- layer 1: xh -> aggH -> h1 ----
    conv1_k<<<(N * 16 + NT - 1) / NT, NT, 0, stream>>>(x, dinv, (int4*)regA, N * 16);
    gather128_k<<<(N + 3) / 4, NT, 0, stream>>>(
        rowptr, srcs, dinv, (const __half2*)regA, (__half2*)regB, N);
    __half* h1 = regA;  // overlays xh (dead)
    mgemm_k<128, true, true, false><<<(N + 63) / 64, NT, 0, stream>>>(
        regB, W1, b1, nullptr, h1, N);

    // ---- layer 2: th = (h1 @ W2) * dinv -> gather -> out ----
    __half* th = regB;  // overlays aggH (dead)
    mgemm_k<64, false, false, true><<<(N + 63) / 64, NT, 0, stream>>>(
        h1, W2, nullptr, dinv, th, N);
    gather64_k<<<(N + 3) / 4, NT, 0, stream>>>(rowptr, srcs, dinv, th, b2, out, N);
}